// Round 1
// baseline (34.759 us; speedup 1.0000x reference)
//
#include <hip/hip_runtime.h>

#define D0 1024
#define D1 512
#define D2 256

// Kernel 1: row sums of W0 (1024 rows x 512) and W1 (512 rows x 256).
// pred[b,i] = avg[b]*sum_j W[i,j] since avg is constant across features.
// One wave per row; f64 accumulate, store f32.
__global__ __launch_bounds__(64) void snn_rowsum(const float* __restrict__ W0,
                                                 const float* __restrict__ W1,
                                                 float* __restrict__ s) {
    const int row  = blockIdx.x;
    const int lane = threadIdx.x;
    const float* base;
    int n;
    if (row < D0) { base = W0 + (size_t)row * D1;        n = D1; }
    else          { base = W1 + (size_t)(row - D0) * D2; n = D2; }
    double acc = 0.0;
    for (int j = lane; j < n; j += 64) acc += (double)base[j];
    #pragma unroll
    for (int off = 32; off >= 1; off >>= 1) acc += __shfl_xor(acc, off, 64);
    if (lane == 0) s[row] = (float)acc;
}

// Kernel 2: one wave per batch row. Per-layer state collapses to scalars
// (v, avg) per row because cur is a [B,1] broadcast and state starts at 0.
__global__ __launch_bounds__(256) void snn_main(const float* __restrict__ x,
                                                const float* __restrict__ s,
                                                const int* __restrict__ ts_ptr,
                                                float* __restrict__ out,
                                                int B) {
    const int lane = threadIdx.x & 63;
    const int wid  = threadIdx.x >> 6;
    const int b    = blockIdx.x * 4 + wid;
    if (b >= B) return;
    const int TS = *ts_ptr;

    float xk[16], s0k[16], s1k[8];
    #pragma unroll
    for (int k = 0; k < 16; ++k) xk[k]  = x[(size_t)b * D0 + (size_t)(k * 64 + lane)];
    #pragma unroll
    for (int k = 0; k < 16; ++k) s0k[k] = s[k * 64 + lane];
    #pragma unroll
    for (int k = 0; k < 8;  ++k) s1k[k] = s[D0 + k * 64 + lane];

    double v0 = 0.0, a0 = 0.0, v1 = 0.0, a1 = 0.0;

    for (int t = 0; t < TS; ++t) {
        const double tf = (double)t;
        const double a0_start = a0, a1_start = a1;

        // ----- layer 0: cur0 = 2 * mean_i |x_i - a0*s0_i| = S0/512 -----
        const float a0f = (float)a0;
        float p0 = 0.f, p1 = 0.f, p2 = 0.f, p3 = 0.f;
        #pragma unroll
        for (int k = 0; k < 16; k += 4) {
            p0 += fabsf(fmaf(-a0f, s0k[k],     xk[k]));
            p1 += fabsf(fmaf(-a0f, s0k[k + 1], xk[k + 1]));
            p2 += fabsf(fmaf(-a0f, s0k[k + 2], xk[k + 2]));
            p3 += fabsf(fmaf(-a0f, s0k[k + 3], xk[k + 3]));
        }
        float acc = (p0 + p1) + (p2 + p3);
        #pragma unroll
        for (int off = 32; off >= 1; off >>= 1) acc += __shfl_xor(acc, off, 64);
        const double cur0 = (double)acc * (1.0 / 512.0);
        v0 = 0.5 * v0 + cur0;
        const double sp0 = (v0 >= 1.0) ? 1.0 : 0.0;
        v0 = (v0 >= 1.0) ? 0.0 : v0;
        a0 = (a0 * tf + sp0) / (tf + 1.0);

        // ----- layer 1: cur1 = 2 * mean_i |a0_new - a1*s1_i| = S1/256 -----
        const float a1f  = (float)a1;
        const float a0nf = (float)a0;
        float q0 = 0.f, q1 = 0.f;
        #pragma unroll
        for (int k = 0; k < 8; k += 2) {
            q0 += fabsf(fmaf(-a1f, s1k[k],     a0nf));
            q1 += fabsf(fmaf(-a1f, s1k[k + 1], a0nf));
        }
        float acc1 = q0 + q1;
        #pragma unroll
        for (int off = 32; off >= 1; off >>= 1) acc1 += __shfl_xor(acc1, off, 64);
        const double cur1 = (double)acc1 * (1.0 / 256.0);
        v1 = 0.5 * v1 + cur1;
        const double sp1 = (v1 >= 1.0) ? 1.0 : 0.0;
        v1 = (v1 >= 1.0) ? 0.0 : v1;
        a1 = (a1 * tf + sp1) / (tf + 1.0);

        // ----- exact fixed point: a0==a1==1, both spiked, v's reset to 0.
        // a0_start==1 (t>=1) implies all prior steps spiked => v_prev was 0
        // => cur >= 1 by itself => every future step is bit-identical, and
        // (1*t+1)/(t+1) == 1.0 exactly. Safe to stop; final a1 == 1.
        if (a0_start == 1.0 && sp0 == 1.0 && a1_start == 1.0 && sp1 == 1.0) break;
    }

    const float r = (float)a1;
    #pragma unroll
    for (int k = 0; k < 4; ++k)
        out[(size_t)b * D2 + (size_t)(k * 64 + lane)] = r;
}

extern "C" void kernel_launch(void* const* d_in, const int* in_sizes, int n_in,
                              void* d_out, int out_size, void* d_ws, size_t ws_size,
                              hipStream_t stream) {
    const float* x  = (const float*)d_in[0];
    const float* W0 = (const float*)d_in[1];
    const float* W1 = (const float*)d_in[2];
    const int*   ts = (const int*)d_in[3];
    float* out = (float*)d_out;
    float* s   = (float*)d_ws;   // s[0..1024) = rowsum(W0), s[1024..1536) = rowsum(W1)
    const int B = in_sizes[0] / D0;

    snn_rowsum<<<D0 + D1, 64, 0, stream>>>(W0, W1, s);
    snn_main<<<(B + 3) / 4, 256, 0, stream>>>(x, s, ts, out, B);
}